// Round 4
// baseline (882.606 us; speedup 1.0000x reference)
//
#include <hip/hip_runtime.h>
#include <stdint.h>
#include <math.h>

typedef __attribute__((ext_vector_type(8))) short short8;
typedef __attribute__((ext_vector_type(8))) unsigned short ushort8;
typedef __attribute__((ext_vector_type(4))) float floatx4;

#define BATCH 4096
#define HID   2048
#define KTOT  4096   // x-half (2048) then h-half (2048)

__device__ __forceinline__ float bf2f(uint16_t u) {
    union { uint32_t i; float f; } v; v.i = ((uint32_t)u) << 16; return v.f;
}
__device__ __forceinline__ uint16_t f2bf(float f) {
    union { uint32_t i; float f; } v; v.f = f;
    uint32_t u = v.i;
    u += 0x7fffu + ((u >> 16) & 1u);   // round-to-nearest-even
    return (uint16_t)(u >> 16);
}
__device__ __forceinline__ float sigmoid_f(float v) {
    return 1.0f / (1.0f + __expf(-v));
}
__device__ __forceinline__ float tanh_f(float v) {
    v = fminf(fmaxf(v, -15.0f), 15.0f);
    float e = __expf(-2.0f * v);
    return (1.0f - e) / (1.0f + e);
}

// Dtype sniff: W_xi ~ U(-0.0221, 0.0221). If the buffer is bf16, every
// half-word decodes to |v| <= 0.0222. If it is f32, the low half-word of
// each float is mantissa noise with a random exponent (P[all 64 pass]
// ~ 5e-11). Deterministic data -> deterministic result -> graph-safe.
__device__ __forceinline__ bool sniff_is_f32(const uint16_t* w) {
    bool big = false;
    for (int j = 0; j < 64; ++j) {
        float v = bf2f(w[j]);
        big |= !(fabsf(v) <= 0.03f);   // NaN also trips this
    }
    return big;
}

// ---------------------------------------------------------------------------
// Fused 4-gate GEMM + LSTM pointwise, templated on input/output dtype.
// Block tile: M=128 x (4 gates x 32 cols), 4 waves (2x2); wave computes
// 64 rows x 16 cols x all 4 gates -> fully in-register epilogue.
// B (K-major W[k][n]) is transposed on the fly into ldsB[n][k] via packed
// dword scatter: wave gw stages gate gw; lane (ng=lane&3, ka=lane>>2) loads
// n-contiguous rows k=2ka, 2ka+1 and packs k-pairs into dwords.
// ---------------------------------------------------------------------------
template<bool F32>
__device__ __forceinline__ void lstm_body(
    const void* xv, const void* hv, const void* cv,
    const void* wxg_v, const void* whg_v,                 // this wave's gate weights
    const void* bvi, const void* bvf, const void* bvo, const void* bvc,
    void* outv)
{
    __shared__ uint16_t ldsA[128 * 32];
    __shared__ uint16_t ldsB[128 * 32];
    uint32_t* ldsB32 = (uint32_t*)ldsB;

    int t    = threadIdx.x;
    int n0   = blockIdx.x * 32;
    int m0   = blockIdx.y * 128;
    int wave = t >> 6, lane = t & 63;
    int wr = wave >> 1, wc = wave & 1;
    int lrow = lane & 15, quad = lane >> 4;
    int srow = t >> 2;          // 0..63 (p adds 64)
    int sseg = (t & 3) * 8;     // k segment 0/8/16/24
    int gw = wave;              // gate staged by this wave
    int ng = lane & 3;          // n-octet
    int ka = lane >> 2;         // k-pair index 0..15

    floatx4 acc[4][4] = {};     // [mi][gate]

    for (int kt = 0; kt < KTOT / 32; ++kt) {
        int k0  = kt * 32;
        int k0h = k0 & (HID - 1);
        bool xhalf = (k0 < HID);

        // ---- global loads into registers (before barrier) ----
        ushort8 va[2];
        uint32_t bw[8];
        if (F32) {
            const float* a = (const float*)(xhalf ? xv : hv);
            #pragma unroll
            for (int p = 0; p < 2; ++p) {
                const float* s = a + (size_t)(m0 + srow + p * 64) * HID + k0h + sseg;
                floatx4 f0 = *(const floatx4*)(s);
                floatx4 f1 = *(const floatx4*)(s + 4);
                #pragma unroll
                for (int j = 0; j < 4; ++j) {
                    va[p][j]     = (short)f2bf(f0[j]);
                    va[p][4 + j] = (short)f2bf(f1[j]);
                }
            }
            const float* wp = (const float*)(xhalf ? wxg_v : whg_v);
            const float* r0p = wp + (size_t)(k0h + 2 * ka) * HID + n0 + ng * 8;
            floatx4 a0 = *(const floatx4*)(r0p);
            floatx4 a1 = *(const floatx4*)(r0p + 4);
            floatx4 b0 = *(const floatx4*)(r0p + HID);
            floatx4 b1 = *(const floatx4*)(r0p + HID + 4);
            #pragma unroll
            for (int j = 0; j < 4; ++j) {
                bw[j]     = (uint32_t)f2bf(a0[j]) | ((uint32_t)f2bf(b0[j]) << 16);
                bw[4 + j] = (uint32_t)f2bf(a1[j]) | ((uint32_t)f2bf(b1[j]) << 16);
            }
        } else {
            const uint16_t* a = (const uint16_t*)(xhalf ? xv : hv);
            #pragma unroll
            for (int p = 0; p < 2; ++p)
                va[p] = *(const ushort8*)(a + (size_t)(m0 + srow + p * 64) * HID + k0h + sseg);
            const uint16_t* wp = (const uint16_t*)(xhalf ? wxg_v : whg_v);
            const uint16_t* r0p = wp + (size_t)(k0h + 2 * ka) * HID + n0 + ng * 8;
            ushort8 r0 = *(const ushort8*)(r0p);
            ushort8 r1 = *(const ushort8*)(r0p + HID);
            #pragma unroll
            for (int j = 0; j < 8; ++j)
                bw[j] = (uint32_t)r0[j] | ((uint32_t)r1[j] << 16);
        }

        __syncthreads();   // previous iteration's fragment reads complete
        #pragma unroll
        for (int p = 0; p < 2; ++p)
            *(ushort8*)(ldsA + (srow + p * 64) * 32 + sseg) = va[p];
        #pragma unroll
        for (int j = 0; j < 8; ++j)
            ldsB32[(gw * 32 + ng * 8 + j) * 16 + ka] = bw[j];
        __syncthreads();   // staged tile visible

        short8 af[4], bfr[4];
        #pragma unroll
        for (int mi = 0; mi < 4; ++mi)
            af[mi] = *(const short8*)(ldsA + (wr * 64 + mi * 16 + lrow) * 32 + quad * 8);
        #pragma unroll
        for (int g = 0; g < 4; ++g)
            bfr[g] = *(const short8*)(ldsB + (g * 32 + wc * 16 + lrow) * 32 + quad * 8);

        #pragma unroll
        for (int mi = 0; mi < 4; ++mi)
            #pragma unroll
            for (int g = 0; g < 4; ++g)
                acc[mi][g] = __builtin_amdgcn_mfma_f32_16x16x32_bf16(
                    af[mi], bfr[g], acc[mi][g], 0, 0, 0);
    }

    // ---- fused LSTM epilogue ----
    int col = n0 + wc * 16 + lrow;
    float Bi, Bf, Bo, Bc;
    if (F32) {
        Bi = ((const float*)bvi)[col]; Bf = ((const float*)bvf)[col];
        Bo = ((const float*)bvo)[col]; Bc = ((const float*)bvc)[col];
    } else {
        Bi = bf2f(((const uint16_t*)bvi)[col]); Bf = bf2f(((const uint16_t*)bvf)[col]);
        Bo = bf2f(((const uint16_t*)bvo)[col]); Bc = bf2f(((const uint16_t*)bvc)[col]);
    }
    int rowb = m0 + wr * 64 + quad * 4;

    #pragma unroll
    for (int mi = 0; mi < 4; ++mi) {
        #pragma unroll
        for (int r = 0; r < 4; ++r) {
            int row = rowb + mi * 16 + r;
            size_t off = (size_t)row * HID + col;
            float gi = sigmoid_f(acc[mi][0][r] + Bi);
            float gf = sigmoid_f(acc[mi][1][r] + Bf);
            float go = sigmoid_f(acc[mi][2][r] + Bo);
            float gc = tanh_f   (acc[mi][3][r] + Bc);
            float cxv = F32 ? ((const float*)cv)[off] : bf2f(((const uint16_t*)cv)[off]);
            float cyv = gf * cxv + gi * gc;
            float hyv = go * tanh_f(cyv);
            if (F32) {
                ((float*)outv)[off] = hyv;
                ((float*)outv)[(size_t)BATCH * HID + off] = cyv;
            } else {
                ((uint16_t*)outv)[off] = f2bf(hyv);
                ((uint16_t*)outv)[(size_t)BATCH * HID + off] = f2bf(cyv);
            }
        }
    }
}

__global__ __launch_bounds__(256) void lstm_fused(
    const void* x, const void* h, const void* cx,
    const void* wxi, const void* whi, const void* wxf, const void* whf,
    const void* wxo, const void* who, const void* wxc, const void* whc,
    const void* bvi, const void* bvf, const void* bvo, const void* bvc,
    void* out)
{
    // per-wave gate weight selection (gate = wave index; order i,f,o,c)
    int gw = (threadIdx.x >> 6);
    const void *wxg, *whg;
    switch (gw) {
        case 0:  wxg = wxi; whg = whi; break;
        case 1:  wxg = wxf; whg = whf; break;
        case 2:  wxg = wxo; whg = who; break;
        default: wxg = wxc; whg = whc; break;
    }
    if (sniff_is_f32((const uint16_t*)wxi))
        lstm_body<true >(x, h, cx, wxg, whg, bvi, bvf, bvo, bvc, out);
    else
        lstm_body<false>(x, h, cx, wxg, whg, bvi, bvf, bvo, bvc, out);
}

extern "C" void kernel_launch(void* const* d_in, const int* in_sizes, int n_in,
                              void* d_out, int out_size, void* d_ws, size_t ws_size,
                              hipStream_t stream) {
    const void* x    = d_in[0];
    const void* h_x  = d_in[1];
    const void* c_x  = d_in[2];
    const void* W_xi = d_in[3];
    const void* W_hi = d_in[4];
    const void* b_i  = d_in[5];
    const void* W_xf = d_in[6];
    const void* W_hf = d_in[7];
    const void* b_f  = d_in[8];
    const void* W_xc = d_in[9];
    const void* W_hc = d_in[10];
    const void* b_c  = d_in[11];
    const void* W_xo = d_in[12];
    const void* W_ho = d_in[13];
    const void* b_o  = d_in[14];

    hipLaunchKernelGGL(lstm_fused, dim3(HID / 32, BATCH / 128), dim3(256), 0, stream,
                       x, h_x, c_x,
                       W_xi, W_hi, W_xf, W_hf, W_xo, W_ho, W_xc, W_hc,
                       b_i, b_f, b_o, b_c, d_out);
}

// Round 5
// 606.129 us; speedup vs baseline: 1.4561x; 1.4561x over previous
//
#include <hip/hip_runtime.h>
#include <stdint.h>

typedef __attribute__((ext_vector_type(8))) short short8;
typedef __attribute__((ext_vector_type(8))) unsigned short ushort8;
typedef __attribute__((ext_vector_type(4))) float floatx4;

#define BATCH 4096
#define HID   2048
#define KTOT  4096   // x-half (2048) then h-half (2048)

__device__ __forceinline__ float bf2f(uint16_t u) {
    union { uint32_t i; float f; } v; v.i = ((uint32_t)u) << 16; return v.f;
}
__device__ __forceinline__ uint16_t f2bf(float f) {
    union { uint32_t i; float f; } v; v.f = f;
    uint32_t u = v.i;
    u += 0x7fffu + ((u >> 16) & 1u);   // round-to-nearest-even
    return (uint16_t)(u >> 16);
}
__device__ __forceinline__ float sigmoid_f(float v) {
    return 1.0f / (1.0f + __expf(-v));
}
__device__ __forceinline__ float tanh_f(float v) {
    v = fminf(fmaxf(v, -15.0f), 15.0f);
    float e = __expf(-2.0f * v);
    return (1.0f - e) / (1.0f + e);
}
__device__ __forceinline__ void load_lds16(const uint16_t* g, uint16_t* l) {
    __builtin_amdgcn_global_load_lds(
        (const __attribute__((address_space(1))) void*)g,
        (__attribute__((address_space(3))) void*)l, 16, 0, 0);
}

// ===========================================================================
// PATH A pre-pass 1: transpose+convert W (f32 K-major) -> wt bf16 [g][n][k],
// k in [0,4096): k<2048 from W_x*, k>=2048 from W_h*. 64x64 tiles via LDS.
// ===========================================================================
__global__ __launch_bounds__(256) void conv_w(
    const float* __restrict__ w0, const float* __restrict__ w1,
    const float* __restrict__ w2, const float* __restrict__ w3,
    const float* __restrict__ w4, const float* __restrict__ w5,
    const float* __restrict__ w6, const float* __restrict__ w7,
    uint16_t* __restrict__ wt)
{
    __shared__ float tile[64][65];
    int b   = blockIdx.x;
    int mi  = b >> 10;          // matrix index = gate*2 + half
    int rem = b & 1023;
    int k0  = (rem >> 5) << 6;
    int n0  = (rem & 31) << 6;
    const float* src;
    switch (mi) {
        case 0: src = w0; break; case 1: src = w1; break;
        case 2: src = w2; break; case 3: src = w3; break;
        case 4: src = w4; break; case 5: src = w5; break;
        case 6: src = w6; break; default: src = w7; break;
    }
    int g = mi >> 1, half = mi & 1;
    int t = threadIdx.x;

    #pragma unroll
    for (int p = 0; p < 4; ++p) {
        int r = (t >> 4) + p * 16;
        int c = (t & 15) * 4;
        floatx4 v = *(const floatx4*)(src + (size_t)(k0 + r) * HID + n0 + c);
        #pragma unroll
        for (int j = 0; j < 4; ++j) tile[r][c + j] = v[j];
    }
    __syncthreads();
    #pragma unroll
    for (int p = 0; p < 2; ++p) {
        int n  = (t >> 3) + p * 32;
        int k8 = (t & 7) * 8;
        ushort8 v;
        #pragma unroll
        for (int j = 0; j < 8; ++j) v[j] = f2bf(tile[k8 + j][n]);
        *(ushort8*)(wt + ((size_t)g * HID + n0 + n) * KTOT + half * HID + k0 + k8) = v;
    }
}

// ===========================================================================
// PATH A pre-pass 2: pack [x | h] f32 -> xh bf16 [4096][4096] row-major.
// ===========================================================================
__global__ __launch_bounds__(256) void conv_a(
    const float* __restrict__ x, const float* __restrict__ h,
    uint16_t* __restrict__ xh)
{
    size_t base = ((size_t)blockIdx.x * 256 + threadIdx.x) * 8;
    int m = (int)(base >> 12);
    int k = (int)(base & (KTOT - 1));
    const float* s = (k < HID) ? (x + (size_t)m * HID + k)
                               : (h + (size_t)m * HID + (k - HID));
    floatx4 f0 = *(const floatx4*)(s);
    floatx4 f1 = *(const floatx4*)(s + 4);
    ushort8 v;
    #pragma unroll
    for (int j = 0; j < 4; ++j) { v[j] = f2bf(f0[j]); v[4 + j] = f2bf(f1[j]); }
    *(ushort8*)(xh + base) = v;
}

// ===========================================================================
// PATH A GEMM: all-bf16 m97-style K-loop (global_load_lds width 16), fused
// LSTM epilogue in f32. Block tile M=128 x (4 gates x 32 cols); wave = 64
// rows x 16 cols x 4 gates -> all gates of a (row,col) in one lane.
// LDS byte offset of thread t is 16*t for both A and B staging -> satisfies
// global_load_lds wave-uniform-base + lane*16 requirement.
// ===========================================================================
__global__ __launch_bounds__(256) void lstm_gemm_bf16(
    const uint16_t* __restrict__ xh, const float* __restrict__ cx,
    const uint16_t* __restrict__ wt,
    const float* __restrict__ bvi, const float* __restrict__ bvf,
    const float* __restrict__ bvo, const float* __restrict__ bvc,
    float* __restrict__ out)
{
    __shared__ uint16_t ldsA[128 * 32];
    __shared__ uint16_t ldsB[128 * 32];

    int t    = threadIdx.x;
    int n0   = blockIdx.x * 32;
    int m0   = blockIdx.y * 128;
    int wave = t >> 6, lane = t & 63;
    int wr = wave >> 1, wc = wave & 1;
    int lrow = lane & 15, quad = lane >> 4;
    int srow = t >> 2;          // 0..63 (p adds 64)
    int sseg = (t & 3) * 8;     // k segment

    // B row for staging (fixed per thread): j = srow + p*64 -> gate, col
    floatx4 acc[4][4] = {};     // [mi][gate]

    for (int kt = 0; kt < KTOT / 32; ++kt) {
        int k0 = kt * 32;

        __syncthreads();   // previous iteration's fragment reads complete
        #pragma unroll
        for (int p = 0; p < 2; ++p) {
            int mr = srow + p * 64;
            load_lds16(xh + (size_t)(m0 + mr) * KTOT + k0 + sseg,
                       ldsA + mr * 32 + sseg);
        }
        #pragma unroll
        for (int p = 0; p < 2; ++p) {
            int j = srow + p * 64;
            int g = j >> 5, dn = j & 31;
            load_lds16(wt + ((size_t)g * HID + n0 + dn) * KTOT + k0 + sseg,
                       ldsB + j * 32 + sseg);
        }
        __syncthreads();   // vmcnt(0) drained before barrier -> tile visible

        short8 af[4], bfr[4];
        #pragma unroll
        for (int mi = 0; mi < 4; ++mi)
            af[mi] = *(const short8*)(ldsA + (wr * 64 + mi * 16 + lrow) * 32 + quad * 8);
        #pragma unroll
        for (int g = 0; g < 4; ++g)
            bfr[g] = *(const short8*)(ldsB + (g * 32 + wc * 16 + lrow) * 32 + quad * 8);

        #pragma unroll
        for (int mi = 0; mi < 4; ++mi)
            #pragma unroll
            for (int g = 0; g < 4; ++g)
                acc[mi][g] = __builtin_amdgcn_mfma_f32_16x16x32_bf16(
                    af[mi], bfr[g], acc[mi][g], 0, 0, 0);
    }

    // ---- fused LSTM epilogue (f32 in/out) ----
    int col = n0 + wc * 16 + lrow;
    float Bi = bvi[col], Bf = bvf[col], Bo = bvo[col], Bc = bvc[col];
    int rowb = m0 + wr * 64 + quad * 4;

    #pragma unroll
    for (int mi = 0; mi < 4; ++mi) {
        #pragma unroll
        for (int r = 0; r < 4; ++r) {
            int row = rowb + mi * 16 + r;
            size_t off = (size_t)row * HID + col;
            float gi = sigmoid_f(acc[mi][0][r] + Bi);
            float gf = sigmoid_f(acc[mi][1][r] + Bf);
            float go = sigmoid_f(acc[mi][2][r] + Bo);
            float gc = tanh_f   (acc[mi][3][r] + Bc);
            float cyv = gf * cx[off] + gi * gc;
            float hyv = go * tanh_f(cyv);
            out[off] = hyv;
            out[(size_t)BATCH * HID + off] = cyv;
        }
    }
}

// ===========================================================================
// PATH B fallback (ws too small): Round-4 proven kernel, f32 hard-coded.
// On-the-fly convert + B transpose through LDS packed-dword scatter.
// ===========================================================================
__global__ __launch_bounds__(256) void lstm_fused_f32(
    const float* __restrict__ x, const float* __restrict__ h,
    const float* __restrict__ cx,
    const float* __restrict__ wxi, const float* __restrict__ whi,
    const float* __restrict__ wxf, const float* __restrict__ whf,
    const float* __restrict__ wxo, const float* __restrict__ who,
    const float* __restrict__ wxc, const float* __restrict__ whc,
    const float* __restrict__ bvi, const float* __restrict__ bvf,
    const float* __restrict__ bvo, const float* __restrict__ bvc,
    float* __restrict__ out)
{
    __shared__ uint16_t ldsA[128 * 32];
    __shared__ uint16_t ldsB[128 * 32];
    uint32_t* ldsB32 = (uint32_t*)ldsB;

    int t    = threadIdx.x;
    int n0   = blockIdx.x * 32;
    int m0   = blockIdx.y * 128;
    int wave = t >> 6, lane = t & 63;
    int wr = wave >> 1, wc = wave & 1;
    int lrow = lane & 15, quad = lane >> 4;
    int srow = t >> 2;
    int sseg = (t & 3) * 8;
    int gw = wave;
    int ng = lane & 3;
    int ka = lane >> 2;
    const float *wxg, *whg;
    switch (gw) {
        case 0:  wxg = wxi; whg = whi; break;
        case 1:  wxg = wxf; whg = whf; break;
        case 2:  wxg = wxo; whg = who; break;
        default: wxg = wxc; whg = whc; break;
    }

    floatx4 acc[4][4] = {};

    for (int kt = 0; kt < KTOT / 32; ++kt) {
        int k0  = kt * 32;
        int k0h = k0 & (HID - 1);
        bool xhalf = (k0 < HID);

        ushort8 va[2];
        uint32_t bw[8];
        const float* a = xhalf ? x : h;
        #pragma unroll
        for (int p = 0; p < 2; ++p) {
            const float* s = a + (size_t)(m0 + srow + p * 64) * HID + k0h + sseg;
            floatx4 f0 = *(const floatx4*)(s);
            floatx4 f1 = *(const floatx4*)(s + 4);
            #pragma unroll
            for (int j = 0; j < 4; ++j) {
                va[p][j]     = (short)f2bf(f0[j]);
                va[p][4 + j] = (short)f2bf(f1[j]);
            }
        }
        const float* wp  = xhalf ? wxg : whg;
        const float* r0p = wp + (size_t)(k0h + 2 * ka) * HID + n0 + ng * 8;
        floatx4 a0 = *(const floatx4*)(r0p);
        floatx4 a1 = *(const floatx4*)(r0p + 4);
        floatx4 b0 = *(const floatx4*)(r0p + HID);
        floatx4 b1 = *(const floatx4*)(r0p + HID + 4);
        #pragma unroll
        for (int j = 0; j < 4; ++j) {
            bw[j]     = (uint32_t)f2bf(a0[j]) | ((uint32_t)f2bf(b0[j]) << 16);
            bw[4 + j] = (uint32_t)f2bf(a1[j]) | ((uint32_t)f2bf(b1[j]) << 16);
        }

        __syncthreads();
        #pragma unroll
        for (int p = 0; p < 2; ++p)
            *(ushort8*)(ldsA + (srow + p * 64) * 32 + sseg) = va[p];
        #pragma unroll
        for (int j = 0; j < 8; ++j)
            ldsB32[(gw * 32 + ng * 8 + j) * 16 + ka] = bw[j];
        __syncthreads();

        short8 af[4], bfr[4];
        #pragma unroll
        for (int mi = 0; mi < 4; ++mi)
            af[mi] = *(const short8*)(ldsA + (wr * 64 + mi * 16 + lrow) * 32 + quad * 8);
        #pragma unroll
        for (int g = 0; g < 4; ++g)
            bfr[g] = *(const short8*)(ldsB + (g * 32 + wc * 16 + lrow) * 32 + quad * 8);

        #pragma unroll
        for (int mi = 0; mi < 4; ++mi)
            #pragma unroll
            for (int g = 0; g < 4; ++g)
                acc[mi][g] = __builtin_amdgcn_mfma_f32_16x16x32_bf16(
                    af[mi], bfr[g], acc[mi][g], 0, 0, 0);
    }

    int col = n0 + wc * 16 + lrow;
    float Bi = bvi[col], Bf = bvf[col], Bo = bvo[col], Bc = bvc[col];
    int rowb = m0 + wr * 64 + quad * 4;

    #pragma unroll
    for (int mi = 0; mi < 4; ++mi) {
        #pragma unroll
        for (int r = 0; r < 4; ++r) {
            int row = rowb + mi * 16 + r;
            size_t off = (size_t)row * HID + col;
            float gi = sigmoid_f(acc[mi][0][r] + Bi);
            float gf = sigmoid_f(acc[mi][1][r] + Bf);
            float go = sigmoid_f(acc[mi][2][r] + Bo);
            float gc = tanh_f   (acc[mi][3][r] + Bc);
            float cyv = gf * cx[off] + gi * gc;
            float hyv = go * tanh_f(cyv);
            out[off] = hyv;
            out[(size_t)BATCH * HID + off] = cyv;
        }
    }
}

extern "C" void kernel_launch(void* const* d_in, const int* in_sizes, int n_in,
                              void* d_out, int out_size, void* d_ws, size_t ws_size,
                              hipStream_t stream) {
    const float* x    = (const float*)d_in[0];
    const float* h_x  = (const float*)d_in[1];
    const float* c_x  = (const float*)d_in[2];
    const float* W_xi = (const float*)d_in[3];
    const float* W_hi = (const float*)d_in[4];
    const float* b_i  = (const float*)d_in[5];
    const float* W_xf = (const float*)d_in[6];
    const float* W_hf = (const float*)d_in[7];
    const float* b_f  = (const float*)d_in[8];
    const float* W_xc = (const float*)d_in[9];
    const float* W_hc = (const float*)d_in[10];
    const float* b_c  = (const float*)d_in[11];
    const float* W_xo = (const float*)d_in[12];
    const float* W_ho = (const float*)d_in[13];
    const float* b_o  = (const float*)d_in[14];

    const size_t WT_BYTES = (size_t)4 * HID * KTOT * sizeof(uint16_t); // 64 MiB
    const size_t XH_BYTES = (size_t)BATCH * KTOT * sizeof(uint16_t);   // 32 MiB

    if (ws_size >= WT_BYTES + XH_BYTES) {
        uint16_t* wt = (uint16_t*)d_ws;
        uint16_t* xh = (uint16_t*)((char*)d_ws + WT_BYTES);
        // gate order i,f,o,c
        hipLaunchKernelGGL(conv_w, dim3(8 * 32 * 32), dim3(256), 0, stream,
                           W_xi, W_hi, W_xf, W_hf, W_xo, W_ho, W_xc, W_hc, wt);
        hipLaunchKernelGGL(conv_a, dim3((BATCH * KTOT) / (256 * 8)), dim3(256), 0, stream,
                           x, h_x, xh);
        hipLaunchKernelGGL(lstm_gemm_bf16, dim3(HID / 32, BATCH / 128), dim3(256), 0, stream,
                           xh, c_x, wt, b_i, b_f, b_o, b_c, (float*)d_out);
    } else {
        hipLaunchKernelGGL(lstm_fused_f32, dim3(HID / 32, BATCH / 128), dim3(256), 0, stream,
                           x, h_x, c_x,
                           W_xi, W_hi, W_xf, W_hf, W_xo, W_ho, W_xc, W_hc,
                           b_i, b_f, b_o, b_c, (float*)d_out);
    }
}

// Round 6
// 500.142 us; speedup vs baseline: 1.7647x; 1.2119x over previous
//
#include <hip/hip_runtime.h>
#include <stdint.h>

typedef __attribute__((ext_vector_type(8))) short short8;
typedef __attribute__((ext_vector_type(8))) unsigned short ushort8;
typedef __attribute__((ext_vector_type(4))) float floatx4;

#define BATCH 4096
#define HID   2048
#define KTOT  4096   // x-half (2048) then h-half (2048)

__device__ __forceinline__ uint16_t f2bf(float f) {
    union { uint32_t i; float f; } v; v.f = f;
    uint32_t u = v.i;
    u += 0x7fffu + ((u >> 16) & 1u);   // round-to-nearest-even
    return (uint16_t)(u >> 16);
}
__device__ __forceinline__ float sigmoid_f(float v) {
    return 1.0f / (1.0f + __expf(-v));
}
__device__ __forceinline__ float tanh_f(float v) {
    v = fminf(fmaxf(v, -15.0f), 15.0f);
    float e = __expf(-2.0f * v);
    return (1.0f - e) / (1.0f + e);
}
__device__ __forceinline__ void load_lds16(const uint16_t* g, uint16_t* l) {
    __builtin_amdgcn_global_load_lds(
        (const __attribute__((address_space(1))) void*)g,
        (__attribute__((address_space(3))) void*)l, 16, 0, 0);
}

// ===========================================================================
// Pre-pass 1: transpose+convert W (f32 K-major) -> wt bf16 [g][n][k4096].
// Pure register transpose: thread owns an 8x8 micro-tile (no LDS -> no
// bank conflicts; R5's LDS version had a 16-way conflict on column reads).
// 128x128 tiles: 8 matrices x 256 tiles = 2048 blocks.
// ===========================================================================
__global__ __launch_bounds__(256) void conv_w(
    const float* __restrict__ w0, const float* __restrict__ w1,
    const float* __restrict__ w2, const float* __restrict__ w3,
    const float* __restrict__ w4, const float* __restrict__ w5,
    const float* __restrict__ w6, const float* __restrict__ w7,
    uint16_t* __restrict__ wt)
{
    int b   = blockIdx.x;
    int mi  = b >> 8;           // matrix index = gate*2 + half
    int rem = b & 255;
    int k0  = (rem >> 4) * 128;
    int n0  = (rem & 15) * 128;
    const float* src;
    switch (mi) {
        case 0: src = w0; break; case 1: src = w1; break;
        case 2: src = w2; break; case 3: src = w3; break;
        case 4: src = w4; break; case 5: src = w5; break;
        case 6: src = w6; break; default: src = w7; break;
    }
    int g = mi >> 1, half = mi & 1;
    int ty = threadIdx.x >> 4, tx = threadIdx.x & 15;
    int kr = k0 + ty * 8;
    int nc = n0 + tx * 8;

    ushort8 a[8];
    #pragma unroll
    for (int j = 0; j < 8; ++j) {
        const float* s = src + (size_t)(kr + j) * HID + nc;
        floatx4 f0 = *(const floatx4*)(s);
        floatx4 f1 = *(const floatx4*)(s + 4);
        #pragma unroll
        for (int i = 0; i < 4; ++i) {
            a[j][i]     = f2bf(f0[i]);
            a[j][4 + i] = f2bf(f1[i]);
        }
    }
    ushort8 bt[8];
    #pragma unroll
    for (int i = 0; i < 8; ++i)
        #pragma unroll
        for (int j = 0; j < 8; ++j)
            bt[i][j] = a[j][i];
    #pragma unroll
    for (int i = 0; i < 8; ++i)
        *(ushort8*)(wt + ((size_t)g * HID + nc + i) * KTOT + half * HID + kr) = bt[i];
}

// ===========================================================================
// Pre-pass 2: pack [x | h] f32 -> xh bf16 [4096][4096] row-major.
// ===========================================================================
__global__ __launch_bounds__(256) void conv_a(
    const float* __restrict__ x, const float* __restrict__ h,
    uint16_t* __restrict__ xh)
{
    size_t base = ((size_t)blockIdx.x * 256 + threadIdx.x) * 8;
    int m = (int)(base >> 12);
    int k = (int)(base & (KTOT - 1));
    const float* s = (k < HID) ? (x + (size_t)m * HID + k)
                               : (h + (size_t)m * HID + (k - HID));
    floatx4 f0 = *(const floatx4*)(s);
    floatx4 f1 = *(const floatx4*)(s + 4);
    ushort8 v;
    #pragma unroll
    for (int j = 0; j < 4; ++j) { v[j] = f2bf(f0[j]); v[4 + j] = f2bf(f1[j]); }
    *(ushort8*)(xh + base) = v;
}

// ===========================================================================
// GEMM: all-bf16, BK=64 K-loop (64 iters, half the barrier drains of R5),
// global_load_lds width-16 staging, fused f32 LSTM epilogue.
// LDS tiles 128 x 64 bf16 (A and B, 16 KB each). Row stride = 128 B = 32
// banks, so fragment rows would fully alias; chunk-XOR swizzle fixes it:
// physical 16B-chunk q of row r holds logical chunk q ^ (r&7). Staging lane
// t loads global chunk (t&7)^(row&7) and stores lane-linear (preserves
// global_load_lds's wave-uniform-base + lane*16 requirement AND global
// coalescing, since the XOR permutes within a 128 B group).
// XCD swizzle: linear%8 = XCD gets 4 fixed my-tiles (4 MB xh slice -> L2).
// ===========================================================================
__global__ __launch_bounds__(256, 4) void lstm_gemm_bf16(
    const uint16_t* __restrict__ xh, const float* __restrict__ cx,
    const uint16_t* __restrict__ wt,
    const float* __restrict__ bvi, const float* __restrict__ bvf,
    const float* __restrict__ bvo, const float* __restrict__ bvc,
    float* __restrict__ out)
{
    __shared__ uint16_t ldsA[128 * 64];   // 16 KB
    __shared__ uint16_t ldsB[128 * 64];   // 16 KB

    int t = threadIdx.x;
    // XCD-aware remap: a=linear&7 (XCD), b=(linear>>3)&3, c=linear>>5
    int linear = blockIdx.y * gridDim.x + blockIdx.x;   // 0..2047
    int my = (linear & 7) * 4 + ((linear >> 3) & 3);    // 0..31
    int nx = linear >> 5;                               // 0..63
    int n0 = nx * 32;
    int m0 = my * 128;

    int wave = t >> 6, lane = t & 63;
    int wr = wave >> 1, wc = wave & 1;
    int lrow = lane & 15, quad = lane >> 4;
    int swz  = lrow & 7;

    int srow = t >> 3;                     // staging row 0..31 (p adds 32)
    int schk = (t & 7) ^ (srow & 7);       // swizzled global chunk index

    floatx4 acc[4][4] = {};                // [mi][gate]

    for (int kt = 0; kt < KTOT / 64; ++kt) {
        int k0 = kt * 64;

        __syncthreads();   // previous iteration's fragment reads complete
        #pragma unroll
        for (int p = 0; p < 4; ++p) {      // A: 128 rows x 64 k
            int row = srow + p * 32;
            load_lds16(xh + (size_t)(m0 + row) * KTOT + k0 + schk * 8,
                       ldsA + p * 2048 + t * 8);
        }
        #pragma unroll
        for (int p = 0; p < 4; ++p) {      // B: 4 gates x 32 cols x 64 k
            int j = srow + p * 32;
            int g = j >> 5, dn = j & 31;
            load_lds16(wt + ((size_t)g * HID + n0 + dn) * KTOT + k0 + schk * 8,
                       ldsB + p * 2048 + t * 8);
        }
        __syncthreads();   // vmcnt drained at barrier -> tile visible

        #pragma unroll
        for (int kh = 0; kh < 2; ++kh) {
            int kkc = kh * 4;              // logical chunk base (k offset /8)
            short8 af[4], bfr[4];
            #pragma unroll
            for (int mi = 0; mi < 4; ++mi)
                af[mi] = *(const short8*)(ldsA + (wr * 64 + mi * 16 + lrow) * 64
                                               + (((quad + kkc) ^ swz)) * 8);
            #pragma unroll
            for (int g = 0; g < 4; ++g)
                bfr[g] = *(const short8*)(ldsB + (g * 32 + wc * 16 + lrow) * 64
                                               + (((quad + kkc) ^ swz)) * 8);
            #pragma unroll
            for (int mi = 0; mi < 4; ++mi)
                #pragma unroll
                for (int g = 0; g < 4; ++g)
                    acc[mi][g] = __builtin_amdgcn_mfma_f32_16x16x32_bf16(
                        af[mi], bfr[g], acc[mi][g], 0, 0, 0);
        }
    }

    // ---- fused LSTM epilogue (f32 in/out) ----
    int col = n0 + wc * 16 + lrow;
    float Bi = bvi[col], Bf = bvf[col], Bo = bvo[col], Bc = bvc[col];
    int rowb = m0 + wr * 64 + quad * 4;

    #pragma unroll
    for (int mi = 0; mi < 4; ++mi) {
        #pragma unroll
        for (int r = 0; r < 4; ++r) {
            int row = rowb + mi * 16 + r;
            size_t off = (size_t)row * HID + col;
            float gi = sigmoid_f(acc[mi][0][r] + Bi);
            float gf = sigmoid_f(acc[mi][1][r] + Bf);
            float go = sigmoid_f(acc[mi][2][r] + Bo);
            float gc = tanh_f   (acc[mi][3][r] + Bc);
            float cyv = gf * cx[off] + gi * gc;
            float hyv = go * tanh_f(cyv);
            out[off] = hyv;
            out[(size_t)BATCH * HID + off] = cyv;
        }
    }
}

// ===========================================================================
// Fallback (ws too small): Round-4 proven fused kernel, f32 inputs.
// ===========================================================================
__global__ __launch_bounds__(256) void lstm_fused_f32(
    const float* __restrict__ x, const float* __restrict__ h,
    const float* __restrict__ cx,
    const float* __restrict__ wxi, const float* __restrict__ whi,
    const float* __restrict__ wxf, const float* __restrict__ whf,
    const float* __restrict__ wxo, const float* __restrict__ who,
    const float* __restrict__ wxc, const float* __restrict__ whc,
    const float* __restrict__ bvi, const float* __restrict__ bvf,
    const float* __restrict__ bvo, const float* __restrict__ bvc,
    float* __restrict__ out)
{
    __shared__ uint16_t ldsA[128 * 32];
    __shared__ uint16_t ldsB[128 * 32];
    uint32_t* ldsB32 = (uint32_t*)ldsB;

    int t    = threadIdx.x;
    int n0   = blockIdx.x * 32;
    int m0   = blockIdx.y * 128;
    int wave = t >> 6, lane = t & 63;
    int wr = wave >> 1, wc = wave & 1;
    int lrow = lane & 15, quad = lane >> 4;
    int srow = t >> 2;
    int sseg = (t & 3) * 8;
    int gw = wave;
    int ng = lane & 3;
    int ka = lane >> 2;
    const float *wxg, *whg;
    switch (gw) {
        case 0:  wxg = wxi; whg = whi; break;
        case 1:  wxg = wxf; whg = whf; break;
        case 2:  wxg = wxo; whg = who; break;
        default: wxg = wxc; whg = whc; break;
    }

    floatx4 acc[4][4] = {};

    for (int kt = 0; kt < KTOT / 32; ++kt) {
        int k0  = kt * 32;
        int k0h = k0 & (HID - 1);
        bool xhalf = (k0 < HID);

        ushort8 va[2];
        uint32_t bw[8];
        const float* a = xhalf ? x : h;
        #pragma unroll
        for (int p = 0; p < 2; ++p) {
            const float* s = a + (size_t)(m0 + srow + p * 64) * HID + k0h + sseg;
            floatx4 f0 = *(const floatx4*)(s);
            floatx4 f1 = *(const floatx4*)(s + 4);
            #pragma unroll
            for (int j = 0; j < 4; ++j) {
                va[p][j]     = (short)f2bf(f0[j]);
                va[p][4 + j] = (short)f2bf(f1[j]);
            }
        }
        const float* wp  = xhalf ? wxg : whg;
        const float* r0p = wp + (size_t)(k0h + 2 * ka) * HID + n0 + ng * 8;
        floatx4 a0 = *(const floatx4*)(r0p);
        floatx4 a1 = *(const floatx4*)(r0p + 4);
        floatx4 b0 = *(const floatx4*)(r0p + HID);
        floatx4 b1 = *(const floatx4*)(r0p + HID + 4);
        #pragma unroll
        for (int j = 0; j < 4; ++j) {
            bw[j]     = (uint32_t)f2bf(a0[j]) | ((uint32_t)f2bf(b0[j]) << 16);
            bw[4 + j] = (uint32_t)f2bf(a1[j]) | ((uint32_t)f2bf(b1[j]) << 16);
        }

        __syncthreads();
        #pragma unroll
        for (int p = 0; p < 2; ++p)
            *(ushort8*)(ldsA + (srow + p * 64) * 32 + sseg) = va[p];
        #pragma unroll
        for (int j = 0; j < 8; ++j)
            ldsB32[(gw * 32 + ng * 8 + j) * 16 + ka] = bw[j];
        __syncthreads();

        short8 af[4], bfr[4];
        #pragma unroll
        for (int mi = 0; mi < 4; ++mi)
            af[mi] = *(const short8*)(ldsA + (wr * 64 + mi * 16 + lrow) * 32 + quad * 8);
        #pragma unroll
        for (int g = 0; g < 4; ++g)
            bfr[g] = *(const short8*)(ldsB + (g * 32 + wc * 16 + lrow) * 32 + quad * 8);

        #pragma unroll
        for (int mi = 0; mi < 4; ++mi)
            #pragma unroll
            for (int g = 0; g < 4; ++g)
                acc[mi][g] = __builtin_amdgcn_mfma_f32_16x16x32_bf16(
                    af[mi], bfr[g], acc[mi][g], 0, 0, 0);
    }

    int col = n0 + wc * 16 + lrow;
    float Bi = bvi[col], Bf = bvf[col], Bo = bvo[col], Bc = bvc[col];
    int rowb = m0 + wr * 64 + quad * 4;

    #pragma unroll
    for (int mi = 0; mi < 4; ++mi) {
        #pragma unroll
        for (int r = 0; r < 4; ++r) {
            int row = rowb + mi * 16 + r;
            size_t off = (size_t)row * HID + col;
            float gi = sigmoid_f(acc[mi][0][r] + Bi);
            float gf = sigmoid_f(acc[mi][1][r] + Bf);
            float go = sigmoid_f(acc[mi][2][r] + Bo);
            float gc = tanh_f   (acc[mi][3][r] + Bc);
            float cyv = gf * cx[off] + gi * gc;
            float hyv = go * tanh_f(cyv);
            out[off] = hyv;
            out[(size_t)BATCH * HID + off] = cyv;
        }
    }
}

extern "C" void kernel_launch(void* const* d_in, const int* in_sizes, int n_in,
                              void* d_out, int out_size, void* d_ws, size_t ws_size,
                              hipStream_t stream) {
    const float* x    = (const float*)d_in[0];
    const float* h_x  = (const float*)d_in[1];
    const float* c_x  = (const float*)d_in[2];
    const float* W_xi = (const float*)d_in[3];
    const float* W_hi = (const float*)d_in[4];
    const float* b_i  = (const float*)d_in[5];
    const float* W_xf = (const float*)d_in[6];
    const float* W_hf = (const float*)d_in[7];
    const float* b_f  = (const float*)d_in[8];
    const float* W_xc = (const float*)d_in[9];
    const float* W_hc = (const float*)d_in[10];
    const float* b_c  = (const float*)d_in[11];
    const float* W_xo = (const float*)d_in[12];
    const float* W_ho = (const float*)d_in[13];
    const float* b_o  = (const float*)d_in[14];

    const size_t WT_BYTES = (size_t)4 * HID * KTOT * sizeof(uint16_t); // 64 MiB
    const size_t XH_BYTES = (size_t)BATCH * KTOT * sizeof(uint16_t);   // 32 MiB

    if (ws_size >= WT_BYTES + XH_BYTES) {
        uint16_t* wt = (uint16_t*)d_ws;
        uint16_t* xh = (uint16_t*)((char*)d_ws + WT_BYTES);
        // gate order i,f,o,c
        hipLaunchKernelGGL(conv_w, dim3(8 * 256), dim3(256), 0, stream,
                           W_xi, W_hi, W_xf, W_hf, W_xo, W_ho, W_xc, W_hc, wt);
        hipLaunchKernelGGL(conv_a, dim3((BATCH * KTOT) / (256 * 8)), dim3(256), 0, stream,
                           x, h_x, xh);
        hipLaunchKernelGGL(lstm_gemm_bf16, dim3(HID / 32, BATCH / 128), dim3(256), 0, stream,
                           xh, c_x, wt, b_i, b_f, b_o, b_c, (float*)d_out);
    } else {
        hipLaunchKernelGGL(lstm_fused_f32, dim3(HID / 32, BATCH / 128), dim3(256), 0, stream,
                           x, h_x, c_x,
                           W_xi, W_hi, W_xf, W_hf, W_xo, W_ho, W_xc, W_hc,
                           b_i, b_f, b_o, b_c, (float*)d_out);
    }
}